// Round 5
// baseline (2220.823 us; speedup 1.0000x reference)
//
#include <hip/hip_runtime.h>
#include <cstdint>
#include <cstddef>

// ---------------------------------------------------------------------------
// ParameterizedKnowledgeStore: out = softmax(q @ (bank@Wk+bk)^T) @ (bank@Wv+bv)
// B*S=8192 queries (Q=512), K=32768 knowledge rows, H=1024.
// R2: softmax fused into score epilogue (fixed stabilizer C=90).
// R3: pv split-K + XCD-aware grid order.
// R4: score GEMM fp16 (no hi/lo split needed; P stays bf16 for exponent range).
// R5: L3-residency chunking R=1024 (P chunk 67MB + kf/VT stay hot in the
//     256MB Infinity Cache -> pv/score staging becomes L3-hit);
//     zsplit=16 (x-stride 16 = 0 mod 8 -> P/VT-sharing blocks same-XCD);
//     LDS XOR swizzle (piece ^= (row>>1)&3, applied on the GLOBAL side of
//     global_load_lds since LDS dest = base+lane*16 is fixed) kills the
//     8-way ds_read_b128 bank conflict; keys GEMM in plain fp16 (FLOPs/3).
// ---------------------------------------------------------------------------

typedef __bf16 bf16_t;
typedef __bf16 bf16x4 __attribute__((ext_vector_type(4)));
typedef __bf16 bf16x8 __attribute__((ext_vector_type(8)));
typedef _Float16 f16_t;
typedef _Float16 f16x4 __attribute__((ext_vector_type(4)));
typedef _Float16 f16x8 __attribute__((ext_vector_type(8)));
typedef float f32x4 __attribute__((ext_vector_type(4)));

#define KS   32768
#define HDIM 1024
#define QDIM 512
#define NQ   8192
#define SOFTMAX_C 90.0f

// ---------------------------------------------------------------------------
__device__ __forceinline__ void async16(const void* g, void* l) {
  __builtin_amdgcn_global_load_lds((const __attribute__((address_space(1))) void*)g,
                                   (__attribute__((address_space(3))) void*)l, 16, 0, 0);
}

// Stage a [128 rows][32 k] tile of 2-byte elems with XOR swizzle.
// LDS slot of lane l is FIXED (chunk base + l*16B): row=c*16+(l>>2), piece=l&3.
// We want slot (r,p) to hold logical piece p ^ ((r>>1)&3), so lane l fetches
// global piece (l&3) ^ ((l>>3)&3)   [(row>>1)&3 == ((l>>2)>>1)&3].
template <typename T>
__device__ __forceinline__ void stage_tile(const T* gbase, size_t ld, int k0,
                                           T* lds, int wave, int lane) {
  const int gp = ((lane & 3) ^ ((lane >> 3) & 3)) * 8;
  for (int c = wave; c < 8; c += 4) {
    const T* g = gbase + (size_t)(c * 16 + (lane >> 2)) * ld + (size_t)k0 + gp;
    async16((const void*)g, (void*)(lds + c * 512));
  }
}

// swizzled element offset for (row, col) in a [128][32] tile (col in elems)
__device__ __forceinline__ int swz(int row, int col) {
  return row * 32 + (((((col >> 3) ^ (row >> 1)) & 3) << 3) | (col & 7));
}

// ---------------------------------------------------------------------------
// prep kernels
// ---------------------------------------------------------------------------
__global__ __launch_bounds__(256) void prep_q(const float* __restrict__ q,
                                              f16_t* __restrict__ qf) {
  int g = blockIdx.x * 256 + threadIdx.x;
  float4 v = *(const float4*)(q + (size_t)g * 4);
  f16x4 h;
  h[0] = (f16_t)v.x; h[1] = (f16_t)v.y; h[2] = (f16_t)v.z; h[3] = (f16_t)v.w;
  *(f16x4*)(qf + (size_t)g * 4) = h;
}

__global__ __launch_bounds__(256) void prep_wk(const float* __restrict__ Wk,
                                               f16_t* __restrict__ WkTf) {
  int t = blockIdx.x * 256 + threadIdx.x;
  int n = t >> 10, k = t & 1023;
  WkTf[t] = (f16_t)Wk[(size_t)k * QDIM + n];
}

__global__ __launch_bounds__(256) void prep_wv(const float* __restrict__ Wv,
                                               bf16_t* __restrict__ WvT) {
  int t = blockIdx.x * 256 + threadIdx.x;
  int n = t >> 10, k = t & 1023;
  WvT[t] = (bf16_t)(Wv[(size_t)k * HDIM + n]);
}

// ---------------------------------------------------------------------------
// keys GEMM (fp16): kf[32768][512] = f16(bank) @ WkTf^T + bk
// ---------------------------------------------------------------------------
__global__ __launch_bounds__(256) void keys_gemm(const float* __restrict__ bank,
                                                 const f16_t* __restrict__ WkTf,
                                                 const float* __restrict__ bk,
                                                 f16_t* __restrict__ kf) {
  __shared__ alignas(16) f16_t lA[128 * 32];
  __shared__ alignas(16) f16_t lB[128 * 32];
  const int tid = threadIdx.x, lane = tid & 63, wave = tid >> 6;
  const int wm = wave & 1, wn = wave >> 1;
  const int qd = lane >> 4, ln = lane & 15;
  const int m0 = blockIdx.y * 128;   // bank rows
  const int n0 = blockIdx.x * 128;   // of 512 key cols
  const int kqs = ((qd ^ ((ln >> 1) & 3)) << 3);   // swizzled frag col offset
  f32x4 acc[4][4] = {};
  for (int k0 = 0; k0 < HDIM; k0 += 32) {
#pragma unroll
    for (int s = 0; s < 4; s++) {
      int g = s * 256 + tid;
      int r = g >> 3, c4 = (g & 7) * 4;
      float4 v = *(const float4*)(bank + (size_t)(m0 + r) * HDIM + k0 + c4);
      f16x4 h;
      h[0] = (f16_t)v.x; h[1] = (f16_t)v.y; h[2] = (f16_t)v.z; h[3] = (f16_t)v.w;
      *(f16x4*)&lA[swz(r, c4)] = h;
    }
    stage_tile(WkTf + (size_t)n0 * HDIM, HDIM, k0, lB, wave, lane);
    __syncthreads();
    f16x8 af[4], bfr[4];
#pragma unroll
    for (int i = 0; i < 4; i++)
      af[i] = *(const f16x8*)&lA[(wm * 64 + i * 16 + ln) * 32 + kqs];
#pragma unroll
    for (int j = 0; j < 4; j++)
      bfr[j] = *(const f16x8*)&lB[(wn * 64 + j * 16 + ln) * 32 + kqs];
#pragma unroll
    for (int i = 0; i < 4; i++)
#pragma unroll
      for (int j = 0; j < 4; j++)
        acc[i][j] = __builtin_amdgcn_mfma_f32_16x16x32_f16(af[i], bfr[j], acc[i][j], 0, 0, 0);
    __syncthreads();
  }
#pragma unroll
  for (int j = 0; j < 4; j++) {
    const int cc = n0 + wn * 64 + j * 16 + ln;
    const float bkc = bk[cc];
#pragma unroll
    for (int i = 0; i < 4; i++) {
      const int rr = m0 + wm * 64 + i * 16 + qd * 4;
#pragma unroll
      for (int r = 0; r < 4; r++)
        kf[(size_t)(rr + r) * QDIM + cc] = (f16_t)(acc[i][j][r] + bkc);
    }
  }
}

// ---------------------------------------------------------------------------
// values GEMM (transposed): VT[h][k] = (bank @ WvT^T + bv)^T, bf16
// ---------------------------------------------------------------------------
__global__ __launch_bounds__(256) void values_gemm_t(const float* __restrict__ bank,
                                                     const bf16_t* __restrict__ WvT,
                                                     const float* __restrict__ bv,
                                                     bf16_t* __restrict__ VT) {
  __shared__ alignas(16) bf16_t lA[128 * 32];
  __shared__ alignas(16) bf16_t lB[128 * 32];
  const int tid = threadIdx.x, lane = tid & 63, wave = tid >> 6;
  const int wm = wave & 1, wn = wave >> 1;
  const int qd = lane >> 4, ln = lane & 15;
  const int m0 = blockIdx.y * 128;   // h rows
  const int n0 = blockIdx.x * 128;   // knowledge cols
  const int kqs = ((qd ^ ((ln >> 1) & 3)) << 3);
  f32x4 acc[4][4] = {};
  for (int k0 = 0; k0 < HDIM; k0 += 32) {
    stage_tile(WvT + (size_t)m0 * HDIM, HDIM, k0, lA, wave, lane);
#pragma unroll
    for (int s = 0; s < 4; s++) {
      int g = s * 256 + tid;
      int r = g >> 3, c4 = (g & 7) * 4;
      float4 v = *(const float4*)(bank + (size_t)(n0 + r) * HDIM + k0 + c4);
      bf16x4 h;
      h[0] = (bf16_t)v.x; h[1] = (bf16_t)v.y; h[2] = (bf16_t)v.z; h[3] = (bf16_t)v.w;
      *(bf16x4*)&lB[swz(r, c4)] = h;
    }
    __syncthreads();
    bf16x8 af[4], bfr[4];
#pragma unroll
    for (int i = 0; i < 4; i++)
      af[i] = *(const bf16x8*)&lA[(wm * 64 + i * 16 + ln) * 32 + kqs];
#pragma unroll
    for (int j = 0; j < 4; j++)
      bfr[j] = *(const bf16x8*)&lB[(wn * 64 + j * 16 + ln) * 32 + kqs];
#pragma unroll
    for (int i = 0; i < 4; i++)
#pragma unroll
      for (int j = 0; j < 4; j++)
        acc[i][j] = __builtin_amdgcn_mfma_f32_16x16x32_bf16(af[i], bfr[j], acc[i][j], 0, 0, 0);
    __syncthreads();
  }
#pragma unroll
  for (int i = 0; i < 4; i++) {
#pragma unroll
    for (int r = 0; r < 4; r++) {
      const int hh = m0 + wm * 64 + i * 16 + qd * 4 + r;
      const float bvc = bv[hh];
#pragma unroll
      for (int j = 0; j < 4; j++) {
        const int cc = n0 + wn * 64 + j * 16 + ln;
        VT[(size_t)hh * KS + cc] = (bf16_t)(acc[i][j][r] + bvc);
      }
    }
  }
}

// ---------------------------------------------------------------------------
// fused score GEMM (fp16, K=512) + softmax-exp: P = bf16(exp(S - C))
// ---------------------------------------------------------------------------
__global__ __launch_bounds__(256) void score_fused(const f16_t* __restrict__ qf,
                                                   const f16_t* __restrict__ kf,
                                                   bf16_t* __restrict__ P,
                                                   float* __restrict__ lpart, int row0) {
  __shared__ alignas(16) f16_t lA[128 * 32];
  __shared__ alignas(16) f16_t lB[128 * 32];
  const int tid = threadIdx.x, lane = tid & 63, wave = tid >> 6;
  const int wm = wave & 1, wn = wave >> 1;
  const int qd = lane >> 4, ln = lane & 15;
  const int m0 = blockIdx.y * 128;    // chunk-relative q rows
  const int n0 = blockIdx.x * 128;    // knowledge cols
  const int kqs = ((qd ^ ((ln >> 1) & 3)) << 3);
  const f16_t* Abase = qf + (size_t)(row0 + m0) * QDIM;
  const f16_t* Bbase = kf + (size_t)n0 * QDIM;
  f32x4 acc[4][4] = {};
  for (int k0 = 0; k0 < QDIM; k0 += 32) {
    stage_tile(Abase, QDIM, k0, lA, wave, lane);
    stage_tile(Bbase, QDIM, k0, lB, wave, lane);
    __syncthreads();
    f16x8 af[4], bfr[4];
#pragma unroll
    for (int i = 0; i < 4; i++)
      af[i] = *(const f16x8*)&lA[(wm * 64 + i * 16 + ln) * 32 + kqs];
#pragma unroll
    for (int j = 0; j < 4; j++)
      bfr[j] = *(const f16x8*)&lB[(wn * 64 + j * 16 + ln) * 32 + kqs];
#pragma unroll
    for (int i = 0; i < 4; i++)
#pragma unroll
      for (int j = 0; j < 4; j++)
        acc[i][j] = __builtin_amdgcn_mfma_f32_16x16x32_f16(af[i], bfr[j], acc[i][j], 0, 0, 0);
    __syncthreads();
  }
  // epilogue: exp, store P (bf16), per-block row sums
  float* ls = (float*)lA;
  if (tid < 128) ls[tid] = 0.f;
  __syncthreads();
  float rsum[4][4];
#pragma unroll
  for (int i = 0; i < 4; i++) {
    const int rr = m0 + wm * 64 + i * 16 + qd * 4;
#pragma unroll
    for (int r = 0; r < 4; r++) rsum[i][r] = 0.f;
#pragma unroll
    for (int j = 0; j < 4; j++) {
      const int cc = n0 + wn * 64 + j * 16 + ln;
#pragma unroll
      for (int r = 0; r < 4; r++) {
        float e = __expf(acc[i][j][r] - SOFTMAX_C);
        bf16_t pb = (bf16_t)e;
        P[(size_t)(rr + r) * KS + cc] = pb;
        rsum[i][r] += (float)pb;
      }
    }
  }
#pragma unroll
  for (int i = 0; i < 4; i++)
#pragma unroll
    for (int r = 0; r < 4; r++) {
#pragma unroll
      for (int off = 1; off < 16; off <<= 1)
        rsum[i][r] += __shfl_xor(rsum[i][r], off);
    }
  if (ln == 0) {
#pragma unroll
    for (int i = 0; i < 4; i++)
#pragma unroll
      for (int r = 0; r < 4; r++)
        atomicAdd(&ls[wm * 64 + i * 16 + qd * 4 + r], rsum[i][r]);
  }
  __syncthreads();
  if (tid < 128)
    lpart[(size_t)(m0 + tid) * (KS / 128) + blockIdx.x] = ls[tid];
}

// ---------------------------------------------------------------------------
// reduce 256 partials per row -> linv = 1/sum
// ---------------------------------------------------------------------------
__global__ __launch_bounds__(256) void lreduce(const float* __restrict__ lpart,
                                               float* __restrict__ linv, int row0) {
  const int row = blockIdx.x;
  float s = lpart[(size_t)row * 256 + threadIdx.x];
#pragma unroll
  for (int off = 32; off; off >>= 1) s += __shfl_xor(s, off);
  __shared__ float red[4];
  if ((threadIdx.x & 63) == 0) red[threadIdx.x >> 6] = s;
  __syncthreads();
  if (threadIdx.x == 0)
    linv[row0 + row] = 1.0f / (red[0] + red[1] + red[2] + red[3]);
}

// ---------------------------------------------------------------------------
// PV GEMM (bf16): out[row][h] (+)= linv[row] * P[row][k] * VT[h][k]
// Grid: x = k-split (16, XCD-aligned), y = m-tile, z = H-tile.
// ---------------------------------------------------------------------------
__global__ __launch_bounds__(256) void pv_gemm(const bf16_t* __restrict__ P,
                                               const bf16_t* __restrict__ VT,
                                               const float* __restrict__ linv,
                                               float* __restrict__ Out, int row0) {
  __shared__ alignas(16) bf16_t lA[128 * 32];
  __shared__ alignas(16) bf16_t lB[128 * 32];
  const int tid = threadIdx.x, lane = tid & 63, wave = tid >> 6;
  const int wm = wave & 1, wn = wave >> 1;
  const int qd = lane >> 4, ln = lane & 15;
  const int m0 = blockIdx.y * 128;          // chunk-relative q rows
  const int n0 = blockIdx.z * 128;          // h cols
  const int kqs = ((qd ^ ((ln >> 1) & 3)) << 3);
  const int kspan = KS / gridDim.x;
  const int kbeg = blockIdx.x * kspan;
  const bf16_t* Abase = P + (size_t)m0 * KS;
  const bf16_t* Bbase = VT + (size_t)n0 * KS;
  f32x4 acc[4][4] = {};
  for (int k0 = kbeg; k0 < kbeg + kspan; k0 += 32) {
    stage_tile(Abase, KS, k0, lA, wave, lane);
    stage_tile(Bbase, KS, k0, lB, wave, lane);
    __syncthreads();
    bf16x8 af[4], bfr[4];
#pragma unroll
    for (int i = 0; i < 4; i++)
      af[i] = *(const bf16x8*)&lA[(wm * 64 + i * 16 + ln) * 32 + kqs];
#pragma unroll
    for (int j = 0; j < 4; j++)
      bfr[j] = *(const bf16x8*)&lB[(wn * 64 + j * 16 + ln) * 32 + kqs];
#pragma unroll
    for (int i = 0; i < 4; i++)
#pragma unroll
      for (int j = 0; j < 4; j++)
        acc[i][j] = __builtin_amdgcn_mfma_f32_16x16x32_bf16(af[i], bfr[j], acc[i][j], 0, 0, 0);
    __syncthreads();
  }
#pragma unroll
  for (int j = 0; j < 4; j++) {
    const int cc = n0 + wn * 64 + j * 16 + ln;
#pragma unroll
    for (int i = 0; i < 4; i++) {
      const int rb = m0 + wm * 64 + i * 16 + qd * 4;
#pragma unroll
      for (int r = 0; r < 4; r++) {
        const int grow = row0 + rb + r;
        float v = acc[i][j][r] * linv[grow];
        float* dst = Out + (size_t)grow * HDIM + cc;
        if (gridDim.x == 1) *dst = v;
        else atomicAdd(dst, v);
      }
    }
  }
}

// ---------------------------------------------------------------------------
extern "C" void kernel_launch(void* const* d_in, const int* in_sizes, int n_in,
                              void* d_out, int out_size, void* d_ws, size_t ws_size,
                              hipStream_t stream) {
  const float* q    = (const float*)d_in[0];
  const float* bank = (const float*)d_in[1];
  const float* Wk   = (const float*)d_in[2];
  const float* bk   = (const float*)d_in[3];
  const float* Wv   = (const float*)d_in[4];
  const float* bv   = (const float*)d_in[5];
  float* out = (float*)d_out;
  char* ws = (char*)d_ws;

  size_t off = 0;
  f16_t*  qf   = (f16_t*)(ws + off);  off += (size_t)NQ * QDIM * 2;
  f16_t*  kf   = (f16_t*)(ws + off);  off += (size_t)KS * QDIM * 2;
  bf16_t* VT   = (bf16_t*)(ws + off); off += (size_t)HDIM * KS * 2;
  f16_t*  wkf  = (f16_t*)(ws + off);  off += (size_t)QDIM * HDIM * 2;
  bf16_t* wvt  = (bf16_t*)(ws + off); off += (size_t)HDIM * HDIM * 2;
  float*  linv = (float*)(ws + off);  off += (size_t)NQ * 4;

  // R=1024: P chunk (67MB) + kf (32MB) / VT (67MB) stay L3-resident
  int R = 1024;
  while (R > 128 && off + (size_t)R * (256 * 4 + KS * 2) > ws_size) R >>= 1;
  float*  lpart = (float*)(ws + off);
  bf16_t* P     = (bf16_t*)(ws + off + (size_t)R * 256 * 4);

  // pv split-K: >= 1024 blocks (4 blocks/CU); x-stride multiple of 8 for XCD
  int zsplit = 1;
  while (8 * (R / 128) * zsplit < 1024 && zsplit < 64) zsplit <<= 1;

  hipMemsetAsync(d_out, 0, (size_t)out_size * sizeof(float), stream);

  prep_q <<<NQ * QDIM / 4 / 256, 256, 0, stream>>>(q, qf);
  prep_wk<<<QDIM * HDIM / 256, 256, 0, stream>>>(Wk, wkf);
  prep_wv<<<HDIM * HDIM / 256, 256, 0, stream>>>(Wv, wvt);
  keys_gemm   <<<dim3(QDIM / 128, KS / 128), 256, 0, stream>>>(bank, wkf, bk, kf);
  values_gemm_t<<<dim3(KS / 128, HDIM / 128), 256, 0, stream>>>(bank, wvt, bv, VT);

  for (int row0 = 0; row0 < NQ; row0 += R) {
    score_fused<<<dim3(KS / 128, R / 128), 256, 0, stream>>>(qf, kf, P, lpart, row0);
    lreduce    <<<R, 256, 0, stream>>>(lpart, linv, row0);
    pv_gemm    <<<dim3(zsplit, R / 128, HDIM / 128), 256, 0, stream>>>(P, VT, linv, out, row0);
  }
}

// Round 6
// 1644.684 us; speedup vs baseline: 1.3503x; 1.3503x over previous
//
#include <hip/hip_runtime.h>
#include <cstdint>
#include <cstddef>

// ---------------------------------------------------------------------------
// ParameterizedKnowledgeStore: out = softmax(q @ (bank@Wk+bk)^T) @ (bank@Wv+bv)
// B*S=8192 queries (Q=512), K=32768 knowledge rows, H=1024.
// R2: softmax fused into score epilogue (fixed stabilizer C=90).
// R3: pv split-K + XCD-aware grid order.
// R4: score GEMM fp16 (P stays bf16 for exponent range).
// R5: LDS XOR swizzle (conflicts -> 0), L3 chunking, fp16 keys.
// R6: bank converted ONCE (prep_bank -> f16 + bf16 copies); keys/values are
//     pure 2-byte all-async GEMMs. Deferred normalization: lpart is global,
//     lreduce folded into one final normalize kernel, pv accumulates
//     unnormalized. R=2048 chunks with zsplit=8 (1024 blocks, 4/CU).
// ---------------------------------------------------------------------------

typedef __bf16 bf16_t;
typedef __bf16 bf16x4 __attribute__((ext_vector_type(4)));
typedef __bf16 bf16x8 __attribute__((ext_vector_type(8)));
typedef _Float16 f16_t;
typedef _Float16 f16x4 __attribute__((ext_vector_type(4)));
typedef _Float16 f16x8 __attribute__((ext_vector_type(8)));
typedef float f32x4 __attribute__((ext_vector_type(4)));

#define KS   32768
#define HDIM 1024
#define QDIM 512
#define NQ   8192
#define SOFTMAX_C 90.0f

// ---------------------------------------------------------------------------
__device__ __forceinline__ void async16(const void* g, void* l) {
  __builtin_amdgcn_global_load_lds((const __attribute__((address_space(1))) void*)g,
                                   (__attribute__((address_space(3))) void*)l, 16, 0, 0);
}

// Stage a [128 rows][32 k] tile of 2-byte elems with XOR swizzle.
// LDS slot of lane l is FIXED (base + l*16B): row=c*16+(l>>2), piece=l&3.
// Slot (r,p) holds logical piece p ^ ((r>>1)&3): lane fetches global piece
// (l&3) ^ ((l>>3)&3).
template <typename T>
__device__ __forceinline__ void stage_tile(const T* gbase, size_t ld, int k0,
                                           T* lds, int wave, int lane) {
  const int gp = ((lane & 3) ^ ((lane >> 3) & 3)) * 8;
  for (int c = wave; c < 8; c += 4) {
    const T* g = gbase + (size_t)(c * 16 + (lane >> 2)) * ld + (size_t)k0 + gp;
    async16((const void*)g, (void*)(lds + c * 512));
  }
}

// ---------------------------------------------------------------------------
// prep kernels
// ---------------------------------------------------------------------------
__global__ __launch_bounds__(256) void prep_q(const float* __restrict__ q,
                                              f16_t* __restrict__ qf) {
  int g = blockIdx.x * 256 + threadIdx.x;
  float4 v = *(const float4*)(q + (size_t)g * 4);
  f16x4 h;
  h[0] = (f16_t)v.x; h[1] = (f16_t)v.y; h[2] = (f16_t)v.z; h[3] = (f16_t)v.w;
  *(f16x4*)(qf + (size_t)g * 4) = h;
}

__global__ __launch_bounds__(256) void prep_bank(const float* __restrict__ bank,
                                                 f16_t* __restrict__ bh,
                                                 bf16_t* __restrict__ bb) {
  size_t g = (size_t)blockIdx.x * 256 + threadIdx.x;
  float4 v = *(const float4*)(bank + g * 4);
  f16x4 h;
  h[0] = (f16_t)v.x; h[1] = (f16_t)v.y; h[2] = (f16_t)v.z; h[3] = (f16_t)v.w;
  *(f16x4*)(bh + g * 4) = h;
  bf16x4 b;
  b[0] = (bf16_t)v.x; b[1] = (bf16_t)v.y; b[2] = (bf16_t)v.z; b[3] = (bf16_t)v.w;
  *(bf16x4*)(bb + g * 4) = b;
}

__global__ __launch_bounds__(256) void prep_wk(const float* __restrict__ Wk,
                                               f16_t* __restrict__ WkTf) {
  int t = blockIdx.x * 256 + threadIdx.x;
  int n = t >> 10, k = t & 1023;
  WkTf[t] = (f16_t)Wk[(size_t)k * QDIM + n];
}

__global__ __launch_bounds__(256) void prep_wv(const float* __restrict__ Wv,
                                               bf16_t* __restrict__ WvT) {
  int t = blockIdx.x * 256 + threadIdx.x;
  int n = t >> 10, k = t & 1023;
  WvT[t] = (bf16_t)(Wv[(size_t)k * HDIM + n]);
}

// ---------------------------------------------------------------------------
// keys GEMM (fp16, all-async): kf[32768][512] = bank_f16 @ WkTf^T + bk
// ---------------------------------------------------------------------------
__global__ __launch_bounds__(256) void keys_gemm(const f16_t* __restrict__ bh,
                                                 const f16_t* __restrict__ WkTf,
                                                 const float* __restrict__ bk,
                                                 f16_t* __restrict__ kf) {
  __shared__ alignas(16) f16_t lA[128 * 32];
  __shared__ alignas(16) f16_t lB[128 * 32];
  const int tid = threadIdx.x, lane = tid & 63, wave = tid >> 6;
  const int wm = wave & 1, wn = wave >> 1;
  const int qd = lane >> 4, ln = lane & 15;
  const int m0 = blockIdx.y * 128;   // bank rows
  const int n0 = blockIdx.x * 128;   // key cols (of 512)
  const int kqs = ((qd ^ ((ln >> 1) & 3)) << 3);
  f32x4 acc[4][4] = {};
  for (int k0 = 0; k0 < HDIM; k0 += 32) {
    stage_tile(bh + (size_t)m0 * HDIM, HDIM, k0, lA, wave, lane);
    stage_tile(WkTf + (size_t)n0 * HDIM, HDIM, k0, lB, wave, lane);
    __syncthreads();
    f16x8 af[4], bfr[4];
#pragma unroll
    for (int i = 0; i < 4; i++)
      af[i] = *(const f16x8*)&lA[(wm * 64 + i * 16 + ln) * 32 + kqs];
#pragma unroll
    for (int j = 0; j < 4; j++)
      bfr[j] = *(const f16x8*)&lB[(wn * 64 + j * 16 + ln) * 32 + kqs];
#pragma unroll
    for (int i = 0; i < 4; i++)
#pragma unroll
      for (int j = 0; j < 4; j++)
        acc[i][j] = __builtin_amdgcn_mfma_f32_16x16x32_f16(af[i], bfr[j], acc[i][j], 0, 0, 0);
    __syncthreads();
  }
#pragma unroll
  for (int j = 0; j < 4; j++) {
    const int cc = n0 + wn * 64 + j * 16 + ln;
    const float bkc = bk[cc];
#pragma unroll
    for (int i = 0; i < 4; i++) {
      const int rr = m0 + wm * 64 + i * 16 + qd * 4;
#pragma unroll
      for (int r = 0; r < 4; r++)
        kf[(size_t)(rr + r) * QDIM + cc] = (f16_t)(acc[i][j][r] + bkc);
    }
  }
}

// ---------------------------------------------------------------------------
// values GEMM (bf16, all-async, transposed out): VT[h][k] = (bank@Wv+bv)^T
// Grid: x = h-tile (8, fastest -> consecutive blocks share the bank k-tile),
//       y = k-tile (256).
// ---------------------------------------------------------------------------
__global__ __launch_bounds__(256) void values_gemm_t(const bf16_t* __restrict__ bb,
                                                     const bf16_t* __restrict__ WvT,
                                                     const float* __restrict__ bv,
                                                     bf16_t* __restrict__ VT) {
  __shared__ alignas(16) bf16_t lA[128 * 32];
  __shared__ alignas(16) bf16_t lB[128 * 32];
  const int tid = threadIdx.x, lane = tid & 63, wave = tid >> 6;
  const int wm = wave & 1, wn = wave >> 1;
  const int qd = lane >> 4, ln = lane & 15;
  const int m0 = blockIdx.x * 128;   // h rows
  const int n0 = blockIdx.y * 128;   // knowledge cols
  const int kqs = ((qd ^ ((ln >> 1) & 3)) << 3);
  f32x4 acc[4][4] = {};
  for (int k0 = 0; k0 < HDIM; k0 += 32) {
    stage_tile(WvT + (size_t)m0 * HDIM, HDIM, k0, lA, wave, lane);
    stage_tile(bb + (size_t)n0 * HDIM, HDIM, k0, lB, wave, lane);
    __syncthreads();
    bf16x8 af[4], bfr[4];
#pragma unroll
    for (int i = 0; i < 4; i++)
      af[i] = *(const bf16x8*)&lA[(wm * 64 + i * 16 + ln) * 32 + kqs];
#pragma unroll
    for (int j = 0; j < 4; j++)
      bfr[j] = *(const bf16x8*)&lB[(wn * 64 + j * 16 + ln) * 32 + kqs];
#pragma unroll
    for (int i = 0; i < 4; i++)
#pragma unroll
      for (int j = 0; j < 4; j++)
        acc[i][j] = __builtin_amdgcn_mfma_f32_16x16x32_bf16(af[i], bfr[j], acc[i][j], 0, 0, 0);
    __syncthreads();
  }
#pragma unroll
  for (int i = 0; i < 4; i++) {
#pragma unroll
    for (int r = 0; r < 4; r++) {
      const int hh = m0 + wm * 64 + i * 16 + qd * 4 + r;
      const float bvc = bv[hh];
#pragma unroll
      for (int j = 0; j < 4; j++) {
        const int cc = n0 + wn * 64 + j * 16 + ln;
        VT[(size_t)hh * KS + cc] = (bf16_t)(acc[i][j][r] + bvc);
      }
    }
  }
}

// ---------------------------------------------------------------------------
// fused score GEMM (fp16, K=512) + softmax-exp: P = bf16(exp(S - C));
// lpart[row][nblock] = block row sums (global rows, no per-chunk reduce).
// ---------------------------------------------------------------------------
__global__ __launch_bounds__(256) void score_fused(const f16_t* __restrict__ qf,
                                                   const f16_t* __restrict__ kf,
                                                   bf16_t* __restrict__ P,
                                                   float* __restrict__ lpart, int row0) {
  __shared__ alignas(16) f16_t lA[128 * 32];
  __shared__ alignas(16) f16_t lB[128 * 32];
  const int tid = threadIdx.x, lane = tid & 63, wave = tid >> 6;
  const int wm = wave & 1, wn = wave >> 1;
  const int qd = lane >> 4, ln = lane & 15;
  const int m0 = blockIdx.y * 128;    // chunk-relative q rows
  const int n0 = blockIdx.x * 128;    // knowledge cols
  const int kqs = ((qd ^ ((ln >> 1) & 3)) << 3);
  const f16_t* Abase = qf + (size_t)(row0 + m0) * QDIM;
  const f16_t* Bbase = kf + (size_t)n0 * QDIM;
  f32x4 acc[4][4] = {};
  for (int k0 = 0; k0 < QDIM; k0 += 32) {
    stage_tile(Abase, QDIM, k0, lA, wave, lane);
    stage_tile(Bbase, QDIM, k0, lB, wave, lane);
    __syncthreads();
    f16x8 af[4], bfr[4];
#pragma unroll
    for (int i = 0; i < 4; i++)
      af[i] = *(const f16x8*)&lA[(wm * 64 + i * 16 + ln) * 32 + kqs];
#pragma unroll
    for (int j = 0; j < 4; j++)
      bfr[j] = *(const f16x8*)&lB[(wn * 64 + j * 16 + ln) * 32 + kqs];
#pragma unroll
    for (int i = 0; i < 4; i++)
#pragma unroll
      for (int j = 0; j < 4; j++)
        acc[i][j] = __builtin_amdgcn_mfma_f32_16x16x32_f16(af[i], bfr[j], acc[i][j], 0, 0, 0);
    __syncthreads();
  }
  // epilogue: exp, store P (bf16), per-block row sums
  float* ls = (float*)lA;
  if (tid < 128) ls[tid] = 0.f;
  __syncthreads();
  float rsum[4][4];
#pragma unroll
  for (int i = 0; i < 4; i++) {
    const int rr = m0 + wm * 64 + i * 16 + qd * 4;
#pragma unroll
    for (int r = 0; r < 4; r++) rsum[i][r] = 0.f;
#pragma unroll
    for (int j = 0; j < 4; j++) {
      const int cc = n0 + wn * 64 + j * 16 + ln;
#pragma unroll
      for (int r = 0; r < 4; r++) {
        float e = __expf(acc[i][j][r] - SOFTMAX_C);
        bf16_t pb = (bf16_t)e;
        P[(size_t)(rr + r) * KS + cc] = pb;
        rsum[i][r] += (float)pb;
      }
    }
  }
#pragma unroll
  for (int i = 0; i < 4; i++)
#pragma unroll
    for (int r = 0; r < 4; r++) {
#pragma unroll
      for (int off = 1; off < 16; off <<= 1)
        rsum[i][r] += __shfl_xor(rsum[i][r], off);
    }
  if (ln == 0) {
#pragma unroll
    for (int i = 0; i < 4; i++)
#pragma unroll
      for (int r = 0; r < 4; r++)
        atomicAdd(&ls[wm * 64 + i * 16 + qd * 4 + r], rsum[i][r]);
  }
  __syncthreads();
  if (tid < 128)
    lpart[(size_t)(row0 + m0 + tid) * (KS / 128) + blockIdx.x] = ls[tid];
}

// ---------------------------------------------------------------------------
// PV GEMM (bf16): out[row][h] += P[row][k] * VT[h][k]   (UNNORMALIZED)
// Grid: x = k-split (8, XCD-aligned stride), y = m-tile, z = H-tile.
// ---------------------------------------------------------------------------
__global__ __launch_bounds__(256) void pv_gemm(const bf16_t* __restrict__ P,
                                               const bf16_t* __restrict__ VT,
                                               float* __restrict__ Out, int row0) {
  __shared__ alignas(16) bf16_t lA[128 * 32];
  __shared__ alignas(16) bf16_t lB[128 * 32];
  const int tid = threadIdx.x, lane = tid & 63, wave = tid >> 6;
  const int wm = wave & 1, wn = wave >> 1;
  const int qd = lane >> 4, ln = lane & 15;
  const int m0 = blockIdx.y * 128;          // chunk-relative q rows
  const int n0 = blockIdx.z * 128;          // h cols
  const int kqs = ((qd ^ ((ln >> 1) & 3)) << 3);
  const int kspan = KS / gridDim.x;
  const int kbeg = blockIdx.x * kspan;
  const bf16_t* Abase = P + (size_t)m0 * KS;
  const bf16_t* Bbase = VT + (size_t)n0 * KS;
  f32x4 acc[4][4] = {};
  for (int k0 = kbeg; k0 < kbeg + kspan; k0 += 32) {
    stage_tile(Abase, KS, k0, lA, wave, lane);
    stage_tile(Bbase, KS, k0, lB, wave, lane);
    __syncthreads();
    bf16x8 af[4], bfr[4];
#pragma unroll
    for (int i = 0; i < 4; i++)
      af[i] = *(const bf16x8*)&lA[(wm * 64 + i * 16 + ln) * 32 + kqs];
#pragma unroll
    for (int j = 0; j < 4; j++)
      bfr[j] = *(const bf16x8*)&lB[(wn * 64 + j * 16 + ln) * 32 + kqs];
#pragma unroll
    for (int i = 0; i < 4; i++)
#pragma unroll
      for (int j = 0; j < 4; j++)
        acc[i][j] = __builtin_amdgcn_mfma_f32_16x16x32_bf16(af[i], bfr[j], acc[i][j], 0, 0, 0);
    __syncthreads();
  }
#pragma unroll
  for (int j = 0; j < 4; j++) {
    const int cc = n0 + wn * 64 + j * 16 + ln;
#pragma unroll
    for (int i = 0; i < 4; i++) {
      const int rb = m0 + wm * 64 + i * 16 + qd * 4;
#pragma unroll
      for (int r = 0; r < 4; r++) {
        const int grow = row0 + rb + r;
        float* dst = Out + (size_t)grow * HDIM + cc;
        if (gridDim.x == 1) *dst = acc[i][j][r];
        else atomicAdd(dst, acc[i][j][r]);
      }
    }
  }
}

// ---------------------------------------------------------------------------
// final: linv = 1/sum(lpart[row]); out[row] *= linv   (one block per row)
// ---------------------------------------------------------------------------
__global__ __launch_bounds__(256) void normalize(const float* __restrict__ lpart,
                                                 float* __restrict__ Out) {
  const int row = blockIdx.x;
  float s = lpart[(size_t)row * 256 + threadIdx.x];
#pragma unroll
  for (int off = 32; off; off >>= 1) s += __shfl_xor(s, off);
  __shared__ float red[4];
  if ((threadIdx.x & 63) == 0) red[threadIdx.x >> 6] = s;
  __syncthreads();
  const float linv = 1.0f / (red[0] + red[1] + red[2] + red[3]);
  float4* o = (float4*)(Out + (size_t)row * HDIM) + threadIdx.x;
  float4 v = *o;
  v.x *= linv; v.y *= linv; v.z *= linv; v.w *= linv;
  *o = v;
}

// ---------------------------------------------------------------------------
extern "C" void kernel_launch(void* const* d_in, const int* in_sizes, int n_in,
                              void* d_out, int out_size, void* d_ws, size_t ws_size,
                              hipStream_t stream) {
  const float* q    = (const float*)d_in[0];
  const float* bank = (const float*)d_in[1];
  const float* Wk   = (const float*)d_in[2];
  const float* bk   = (const float*)d_in[3];
  const float* Wv   = (const float*)d_in[4];
  const float* bv   = (const float*)d_in[5];
  float* out = (float*)d_out;
  char* ws = (char*)d_ws;

  size_t off = 0;
  f16_t*  qf    = (f16_t*)(ws + off);  off += (size_t)NQ * QDIM * 2;
  f16_t*  kf    = (f16_t*)(ws + off);  off += (size_t)KS * QDIM * 2;
  bf16_t* VT    = (bf16_t*)(ws + off); off += (size_t)HDIM * KS * 2;
  f16_t*  bkf16 = (f16_t*)(ws + off);  off += (size_t)KS * HDIM * 2;   // bank f16
  bf16_t* bkbf  = (bf16_t*)(ws + off); off += (size_t)KS * HDIM * 2;   // bank bf16
  f16_t*  wkf   = (f16_t*)(ws + off);  off += (size_t)QDIM * HDIM * 2;
  bf16_t* wvt   = (bf16_t*)(ws + off); off += (size_t)HDIM * HDIM * 2;
  float*  lpart = (float*)(ws + off);  off += (size_t)NQ * 256 * 4;

  // R=2048: P chunk (134MB) + VT (67MB) + out-chunk stay ~L3-resident
  int R = 2048;
  while (R > 128 && off + (size_t)R * KS * 2 > ws_size) R >>= 1;
  bf16_t* P = (bf16_t*)(ws + off);

  // pv split-K: 8*(R/128)*z blocks; target 1024 (4/CU), x-stride mult of 8
  int zsplit = 16384 / R;
  if (zsplit < 1) zsplit = 1;
  if (zsplit > 64) zsplit = 64;

  hipMemsetAsync(d_out, 0, (size_t)out_size * sizeof(float), stream);

  prep_q   <<<NQ * QDIM / 4 / 256, 256, 0, stream>>>(q, qf);
  prep_bank<<<KS * HDIM / 4 / 256, 256, 0, stream>>>(bank, bkf16, bkbf);
  prep_wk  <<<QDIM * HDIM / 256, 256, 0, stream>>>(Wk, wkf);
  prep_wv  <<<HDIM * HDIM / 256, 256, 0, stream>>>(Wv, wvt);
  keys_gemm    <<<dim3(QDIM / 128, KS / 128), 256, 0, stream>>>(bkf16, wkf, bk, kf);
  values_gemm_t<<<dim3(HDIM / 128, KS / 128), 256, 0, stream>>>(bkbf, wvt, bv, VT);

  for (int row0 = 0; row0 < NQ; row0 += R) {
    score_fused<<<dim3(KS / 128, R / 128), 256, 0, stream>>>(qf, kf, P, lpart, row0);
    pv_gemm    <<<dim3(zsplit, R / 128, HDIM / 128), 256, 0, stream>>>(P, VT, out, row0);
  }
  normalize<<<NQ, 256, 0, stream>>>(lpart, out);
}